// Round 1
// baseline (2535.864 us; speedup 1.0000x reference)
//
#include <hip/hip_runtime.h>

#define NB 1024   // boxes
#define NC 151    // classes
#define DF 4096   // feature dim

// ---------------- GEMM: dists = fmap @ W + b (fp32, double accum) ----------------
__global__ __launch_bounds__(192) void gemm_kernel(
    const float* __restrict__ fmap, const float* __restrict__ W,
    const float* __restrict__ bias, float* __restrict__ dists) {
  __shared__ float sf[2 * DF];  // two fmap rows, 32 KiB
  int r0 = blockIdx.x * 2;
  const float4* src = (const float4*)(fmap + (size_t)r0 * DF);
  float4* dst = (float4*)sf;
  for (int i = threadIdx.x; i < 2 * DF / 4; i += 192) dst[i] = src[i];
  __syncthreads();
  int c = threadIdx.x;
  if (c < NC) {
    double a0 = 0.0, a1 = 0.0;
    const float* w = W + c;
#pragma unroll 4
    for (int d = 0; d < DF; ++d) {
      double wv = (double)w[(size_t)d * NC];
      a0 += (double)sf[d] * wv;
      a1 += (double)sf[DF + d] * wv;
    }
    float b = bias[c];
    dists[(size_t)r0 * NC + c] = (float)a0 + b;
    dists[((size_t)r0 + 1) * NC + c] = (float)a1 + b;
  }
}

// ---------------- softmax rows, zero background col ----------------
__global__ __launch_bounds__(64) void softmax_kernel(
    const float* __restrict__ dists, float* __restrict__ probs) {
  int row = blockIdx.x;
  int t = threadIdx.x;
  const float* x = dists + (size_t)row * NC;
  float v0 = x[t];
  float v1 = x[t + 64];
  float v2 = (t + 128 < NC) ? x[t + 128] : -3.0e38f;
  float m = fmaxf(fmaxf(v0, v1), v2);
  for (int off = 32; off; off >>= 1) m = fmaxf(m, __shfl_down(m, off));
  m = __shfl(m, 0);
  float e0 = expf(v0 - m), e1 = expf(v1 - m);
  float e2 = (t + 128 < NC) ? expf(v2 - m) : 0.0f;
  float s = e0 + e1 + e2;
  for (int off = 32; off; off >>= 1) s += __shfl_down(s, off);
  s = __shfl(s, 0);
  float* p = probs + (size_t)row * NC;
  p[t] = (t == 0) ? 0.0f : (e0 / s);
  p[t + 64] = e1 / s;
  if (t + 128 < NC) p[t + 128] = e2 / s;
}

// ---------------- transpose boxes to [C][N][4], precompute areas [C][N] ----------------
__global__ __launch_bounds__(256) void transpose_kernel(
    const float* __restrict__ boxes, float* __restrict__ boxes_t,
    float* __restrict__ area_t) {
#pragma clang fp contract(off)
  int idx = blockIdx.x * 256 + threadIdx.x;  // idx = c*NB + n
  if (idx >= NC * NB) return;
  int c = idx >> 10;          // / NB
  int n = idx & (NB - 1);     // % NB
  float4 b = *(const float4*)(boxes + ((size_t)n * NC + c) * 4);
  *(float4*)(boxes_t + (size_t)idx * 4) = b;
  area_t[idx] = (b.z - b.x + 1.0f) * (b.w - b.y + 1.0f);
}

// ---------------- greedy commit: single block, incremental row-max ----------------
__global__ __launch_bounds__(256) void greedy_kernel(
    float* probs, const float* __restrict__ boxes_t,
    const float* __restrict__ area_t, float* __restrict__ out_preds) {
#pragma clang fp contract(off)
  __shared__ float s_rowmax[NB];
  __shared__ int s_rowarg[NB];
  __shared__ int s_comm[NB];
  __shared__ int s_commits[NB];
  __shared__ float s_wval[4];
  __shared__ int s_wrow[4];
  __shared__ int s_b, s_cl;
  __shared__ float4 s_boxb;
  __shared__ float s_areab;

  int t = threadIdx.x;

  // init row maxima (thread t owns rows r with r % 256 == t, forever)
  for (int r = t; r < NB; r += 256) {
    const float* p = probs + (size_t)r * NC;
    float m = p[0];  // col 0 is 0
    int a = 0;
    for (int c = 1; c < NC; ++c) {
      float v = p[c];
      if (v > m) { m = v; a = c; }
    }
    s_rowmax[r] = m; s_rowarg[r] = a;
    s_comm[r] = 0; s_commits[r] = 0;
  }
  __syncthreads();

  for (int it = 0; it < NB; ++it) {
    // ---- phase 1: global argmax over (rowmax, row), ties -> smaller row ----
    float bv = s_rowmax[t];
    int br = t;
    for (int k = 1; k < 4; ++k) {
      int r = t + k * 256;
      float v = s_rowmax[r];
      if (v > bv || (v == bv && r < br)) { bv = v; br = r; }
    }
    for (int off = 32; off; off >>= 1) {
      float ov = __shfl_down(bv, off);
      int orr = __shfl_down(br, off);
      if (ov > bv || (ov == bv && orr < br)) { bv = ov; br = orr; }
    }
    int wave = t >> 6;
    if ((t & 63) == 0) { s_wval[wave] = bv; s_wrow[wave] = br; }
    __syncthreads();
    if (t == 0) {
      float v = s_wval[0]; int r = s_wrow[0];
      for (int w = 1; w < 4; ++w)
        if (s_wval[w] > v || (s_wval[w] == v && s_wrow[w] < r)) { v = s_wval[w]; r = s_wrow[w]; }
      int cl = s_rowarg[r];
      s_b = r; s_cl = cl;
      s_commits[r] = cl;
      s_boxb = *(const float4*)(boxes_t + ((size_t)cl * NB + r) * 4);
      s_areab = area_t[(size_t)cl * NB + r];
    }
    __syncthreads();

    int b = s_b, cl = s_cl;
    float4 boxb = s_boxb;
    float areab = s_areab;

    // ---- phase 2: suppress column cl where IoU >= 0.5 ----
    for (int k = 0; k < 4; ++k) {
      int r = t + k * 256;
      if (r == b) continue;  // row b is reset below; its probs are never read again
      float4 bj = *(const float4*)(boxes_t + ((size_t)cl * NB + r) * 4);
      float ix = fminf(boxb.z, bj.z) - fmaxf(boxb.x, bj.x) + 1.0f;
      float iy = fminf(boxb.w, bj.w) - fmaxf(boxb.y, bj.y) + 1.0f;
      ix = fmaxf(ix, 0.0f);
      iy = fmaxf(iy, 0.0f);
      float inter = ix * iy;
      float uni = area_t[(size_t)cl * NB + r] + areab - inter;
      float iou = inter / uni;
      if (iou >= 0.5f) {
        if (s_comm[r]) {
          // committed row: p[r,*] is -1 except previously re-zeroed cols (value 0)
          if (s_rowmax[r] < 0.0f) { s_rowmax[r] = 0.0f; s_rowarg[r] = cl; }
          else if (cl < s_rowarg[r]) { s_rowarg[r] = cl; }
        } else {
          float* pp = probs + (size_t)r * NC;
          pp[cl] = 0.0f;
          if (s_rowarg[r] == cl) {  // max may have dropped: rescan
            float m = pp[0];
            int a = 0;
            for (int c = 1; c < NC; ++c) {
              float v = pp[c];
              if (v > m) { m = v; a = c; }
            }
            s_rowmax[r] = m; s_rowarg[r] = a;
          }
        }
      }
    }
    __syncthreads();
    if (t == 0) { s_comm[b] = 1; s_rowmax[b] = -1.0f; }
    __syncthreads();
  }

  for (int r = t; r < NB; r += 256) out_preds[r] = (float)s_commits[r];
}

// ---------------- host ----------------
extern "C" void kernel_launch(void* const* d_in, const int* in_sizes, int n_in,
                              void* d_out, int out_size, void* d_ws, size_t ws_size,
                              hipStream_t stream) {
  const float* obj_fmap = (const float*)d_in[0];  // [NB, DF]
  const float* W_out    = (const float*)d_in[1];  // [DF, NC]
  const float* b_out    = (const float*)d_in[2];  // [NC]
  const float* boxes    = (const float*)d_in[3];  // [NB, NC, 4]

  float* out_dists = (float*)d_out;            // NB*NC
  float* out_preds = (float*)d_out + NB * NC;  // NB (written as float)

  float* probs   = (float*)d_ws;                       // NB*NC
  float* boxes_t = probs + (size_t)NB * NC;            // NC*NB*4
  float* area_t  = boxes_t + (size_t)NC * NB * 4;      // NC*NB

  gemm_kernel<<<NB / 2, 192, 0, stream>>>(obj_fmap, W_out, b_out, out_dists);
  softmax_kernel<<<NB, 64, 0, stream>>>(out_dists, probs);
  transpose_kernel<<<(NC * NB + 255) / 256, 256, 0, stream>>>(boxes, boxes_t, area_t);
  greedy_kernel<<<1, 256, 0, stream>>>(probs, boxes_t, area_t, out_preds);
}